// Round 1
// baseline (839.440 us; speedup 1.0000x reference)
//
#include <hip/hip_runtime.h>

#define TT 1024
#define BB 2048

// ---------------------------------------------------------------------------
// tanh(x) = 1 - 2/(exp2(2*log2(e)*x) + 1)
// Branch-free, correct for both signs, saturates exactly to +/-1 at +/-inf.
// 5 ops: mul, exp2(transc), add, rcp(transc), fma.
__device__ __forceinline__ float tanh_fast(float x) {
  float e = __builtin_amdgcn_exp2f(x * 2.8853900817779268f); // 2*log2(e)
  float r = __builtin_amdgcn_rcpf(e + 1.0f);
  return fmaf(-2.0f, r, 1.0f);
}

// DPP butterfly step: add a lane-permuted copy (VALU pipe, not DS pipe).
template <int CTRL>
__device__ __forceinline__ float dpp_step(float x) {
  int y = __builtin_amdgcn_update_dpp(0, __float_as_int(x), CTRL, 0xF, 0xF, true);
  return x + __int_as_float(y);
}

// Sum across each aligned 16-lane group; result replicated in all 16 lanes.
// quad_perm xor1 (0xB1), quad_perm xor2 (0x4E), row_half_mirror (0x141),
// row_mirror (0x140).
__device__ __forceinline__ float sum16(float x) {
  x = dpp_step<0xB1>(x);
  x = dpp_step<0x4E>(x);
  x = dpp_step<0x141>(x);
  x = dpp_step<0x140>(x);
  return x;
}

// ---------------------------------------------------------------------------
// Phase 1: sequential RK4 scan of x (3 floats / element).
// 16 lanes per element (lane j = hidden unit j of all three 1->16->1 NNs).
// Normalized-coordinate dynamics (all scale constants folded):
//   ka = 0.1*(u + 2 - ca) - f1(ca)
//   kb = -0.1*cb - 1/6 + (5/3) f1 - 3 f2 + f3
//   kc = -0.1*cc - 1/6 + f2 - f3
// where fi = sum_j W1[j]*tanh(W0[j]*c + b0[j]) + b1  (b1 folded into consts).
__global__ __launch_bounds__(256) void phase1_kernel(
    const float* __restrict__ useq, const float* __restrict__ x0,
    const float* __restrict__ r1W0, const float* __restrict__ r1b0,
    const float* __restrict__ r1W1, const float* __restrict__ r1b1,
    const float* __restrict__ r2W0, const float* __restrict__ r2b0,
    const float* __restrict__ r2W1, const float* __restrict__ r2b1,
    const float* __restrict__ r3W0, const float* __restrict__ r3b0,
    const float* __restrict__ r3W1, const float* __restrict__ r3b1,
    float* __restrict__ out) {
  const int tid = threadIdx.x;
  const int e = blockIdx.x * 16 + (tid >> 4);  // batch element
  const int j = tid & 15;                      // hidden unit

  // Per-lane weights for the three reaction NNs (held in VGPRs).
  const float w01 = r1W0[j], bb01 = r1b0[j], w11 = r1W1[j];
  const float w02 = r2W0[j], bb02 = r2b0[j], w12 = r2W1[j];
  const float w03 = r3W0[j], bb03 = r3b0[j], w13 = r3W1[j];
  const float b11 = r1b1[0], b12 = r2b1[0], b13 = r3b1[0];

  float ca = x0[e * 15 + 0];
  float cb = x0[e * 15 + 1];
  float cc = x0[e * 15 + 2];

  // b1 biases folded into additive constants.
  const float caC = 0.2f - b11;  // used as ut = 0.1*u + caC
  const float cbC = -1.0f / 6.0f + (5.0f / 3.0f) * b11 - 3.0f * b12 + b13;
  const float ccC = -1.0f / 6.0f + b12 - b13;

  const float* up = useq + e * TT;
  float* op = out + (size_t)e * TT * 4;

#define FEVAL(A, B, C, KA, KB, KC)                                  \
  {                                                                 \
    float s1 = sum16(w11 * tanh_fast(fmaf(w01, (A), bb01)));        \
    float s2 = sum16(w12 * tanh_fast(fmaf(w02, (B), bb02)));        \
    float s3 = sum16(w13 * tanh_fast(fmaf(w03, (C), bb03)));        \
    KA = fmaf(-0.1f, (A), ut) - s1;                                 \
    KB = fmaf(-0.1f, (B), cbC) +                                    \
         fmaf(5.0f / 3.0f, s1, fmaf(-3.0f, s2, s3));                \
    KC = fmaf(-0.1f, (C), ccC) + (s2 - s3);                         \
  }

  float unext = up[0];
  for (int t = 0; t < TT; ++t) {
    float u = unext;
    unext = up[(t + 1 < TT) ? (t + 1) : (TT - 1)];  // prefetch next step's u
    float ut = fmaf(0.1f, u, caC);

    // Emit y[b,t,0:3] = x_t (state BEFORE update). Lanes 0..2 write.
    float xv = (j == 0) ? ca : ((j == 1) ? cb : cc);
    if (j < 3) op[t * 4 + j] = xv;

    float k1a, k1b, k1c, k2a, k2b, k2c, k3a, k3b, k3c, k4a, k4b, k4c;
    FEVAL(ca, cb, cc, k1a, k1b, k1c)
    float xa = fmaf(0.5f, k1a, ca);
    float xb = fmaf(0.5f, k1b, cb);
    float xc = fmaf(0.5f, k1c, cc);
    FEVAL(xa, xb, xc, k2a, k2b, k2c)
    xa = fmaf(0.5f, k2a, ca);
    xb = fmaf(0.5f, k2b, cb);
    xc = fmaf(0.5f, k2c, cc);
    FEVAL(xa, xb, xc, k3a, k3b, k3c)
    xa = ca + k3a;
    xb = cb + k3b;
    xc = cc + k3c;
    FEVAL(xa, xb, xc, k4a, k4b, k4c)

    ca = fmaf(1.0f / 6.0f, k1a + 2.0f * (k2a + k3a) + k4a, ca);
    cb = fmaf(1.0f / 6.0f, k1b + 2.0f * (k2b + k3b) + k4b, cb);
    cc = fmaf(1.0f / 6.0f, k1c + 2.0f * (k2c + k3c) + k4c, cc);
  }
#undef FEVAL
}

// ---------------------------------------------------------------------------
// Phase 2: out[b,t,3] = estC(z_t), fully parallel over (b,t).
// z_t is a delay line: pairs i=0..3 -> x_{t-4+i}[0:2] (or z0 for t-4+i<0),
// u slots i=0..3 -> u_{t-4+i} (or z0). x-history comes from out[.,.,0:2]
// written by phase 1 (ordered: same stream, earlier launch).
// Each 32-lane half-wave = one sample; lane h = hidden unit h (of 32).
__global__ __launch_bounds__(256) void phase2_kernel(
    const float* __restrict__ useq, const float* __restrict__ x0,
    const float* __restrict__ W0, const float* __restrict__ b0,
    const float* __restrict__ W1, const float* __restrict__ b1p,
    float* __restrict__ out) {
  const int h = threadIdx.x & 31;  // hidden unit
  // Per-lane column of W0 (12x32 row-major) + bias + output weight.
  float w[12];
#pragma unroll
  for (int i = 0; i < 12; ++i) w[i] = W0[i * 32 + h];
  const float bb = b0[h];
  const float w1 = W1[h];
  const float b1 = b1p[0];

  const int gw = (int)((blockIdx.x * blockDim.x + threadIdx.x) >> 6);  // wave id
  const int half = (threadIdx.x >> 5) & 1;
  const int nw = (int)((gridDim.x * blockDim.x) >> 6);
  const int totalPairs = (BB * TT) / 2;

  for (int p = gw; p < totalPairs; p += nw) {
    const int s = p * 2 + half;   // sample = b*1024 + t
    const int b = s >> 10;
    const int t = s & 1023;
    const float* xrow = x0 + b * 15;

    float z[12];
#pragma unroll
    for (int i = 0; i < 4; ++i) {
      const int s4 = t - 4 + i;
      // y-history pair (branchless pointer select; both sides stride-1).
      const float* py = (s4 >= 0) ? (out + ((size_t)(b << 10) + s4) * 4)
                                  : (xrow + 3 + 2 * (i + t));
      z[2 * i] = py[0];
      z[2 * i + 1] = py[1];
      // u-history slot.
      const float* pu = (s4 >= 0) ? (useq + (b << 10) + s4)
                                  : (xrow + 11 + i + t);
      z[8 + i] = pu[0];
    }

    float acc = bb;
#pragma unroll
    for (int i = 0; i < 12; ++i) acc = fmaf(z[i], w[i], acc);
    float pv = w1 * tanh_fast(acc);

    // Reduce 32 lanes within this half: 16-lane DPP butterfly + xor16 swizzle.
    pv = sum16(pv);
    pv += __int_as_float(
        __builtin_amdgcn_ds_swizzle(__float_as_int(pv), 0x401F));  // xor 16

    if (h == 0) out[(size_t)s * 4 + 3] = pv + b1;
  }
}

// ---------------------------------------------------------------------------
extern "C" void kernel_launch(void* const* d_in, const int* in_sizes, int n_in,
                              void* d_out, int out_size, void* d_ws,
                              size_t ws_size, hipStream_t stream) {
  const float* useq = (const float*)d_in[0];
  const float* x0 = (const float*)d_in[1];
  float* out = (float*)d_out;

  phase1_kernel<<<BB / 16, 256, 0, stream>>>(
      useq, x0,
      (const float*)d_in[2], (const float*)d_in[3], (const float*)d_in[4],
      (const float*)d_in[5], (const float*)d_in[6], (const float*)d_in[7],
      (const float*)d_in[8], (const float*)d_in[9], (const float*)d_in[10],
      (const float*)d_in[11], (const float*)d_in[12], (const float*)d_in[13],
      out);

  phase2_kernel<<<4096, 256, 0, stream>>>(
      useq, x0, (const float*)d_in[14], (const float*)d_in[15],
      (const float*)d_in[16], (const float*)d_in[17], out);
}

// Round 2
// 544.799 us; speedup vs baseline: 1.5408x; 1.5408x over previous
//
#include <hip/hip_runtime.h>

#define TT 1024
#define BB 2048
#define K1 8  // phase-1 chunk: steps per u-prefetch / store batch

// ---------------------------------------------------------------------------
// 2*log2(e): tanh(x) = 1 - 2*rcp(exp2(L2E2*x) + 1)
#define L2E2 2.8853900817779268f

// DPP butterfly step: add a lane-permuted copy (VALU pipe, not DS pipe).
template <int CTRL>
__device__ __forceinline__ float dpp_step(float x) {
  int y = __builtin_amdgcn_update_dpp(0, __float_as_int(x), CTRL, 0xF, 0xF, true);
  return x + __int_as_float(y);
}

// Sum across each aligned 16-lane group; result replicated in all 16 lanes.
__device__ __forceinline__ float sum16(float x) {
  x = dpp_step<0xB1>(x);   // quad_perm xor1
  x = dpp_step<0x4E>(x);   // quad_perm xor2
  x = dpp_step<0x141>(x);  // row_half_mirror (xor4)
  x = dpp_step<0x140>(x);  // row_mirror (xor8)
  return x;
}

// ---------------------------------------------------------------------------
// Phase 1: sequential RK4 scan of x. 16 lanes per element, 4 elements/wave,
// 512 waves (512 blocks x 64 threads -> 2 blocks/CU, 1 wave/SIMD).
// All memory ops hoisted out of the per-step chain:
//   - u prefetched one 8-step chunk ahead (2x float4),
//   - y-outputs staged in regs, 8 stores batched per chunk.
// Math (normalized coords, C_i = b1_i + sum_j w1_ij folded into constants,
// P_i = sum16((-2 w1)*rcp(exp2(w0s*c+b0s)+1))):
//   ka = fma(-0.1,A,ut) - P1,              ut  = fma(0.1,u, 0.2 - C1)
//   kb = fma(-0.1,B,cbC) + (5/3)P1 - 3P2 + P3
//   kc = fma(-0.1,C,ccC) + P2 - P3
__global__ __launch_bounds__(64) void phase1_kernel(
    const float* __restrict__ useq, const float* __restrict__ x0,
    const float* __restrict__ r1W0, const float* __restrict__ r1b0,
    const float* __restrict__ r1W1, const float* __restrict__ r1b1,
    const float* __restrict__ r2W0, const float* __restrict__ r2b0,
    const float* __restrict__ r2W1, const float* __restrict__ r2b1,
    const float* __restrict__ r3W0, const float* __restrict__ r3b0,
    const float* __restrict__ r3W1, const float* __restrict__ r3b1,
    float* __restrict__ out) {
  const int j = threadIdx.x & 15;
  const int e = blockIdx.x * 4 + (threadIdx.x >> 4);

  // Per-lane folded weights (VGPR-resident).
  const float w01 = r1W0[j] * L2E2, b01 = r1b0[j] * L2E2, wn1 = -2.0f * r1W1[j];
  const float w02 = r2W0[j] * L2E2, b02 = r2b0[j] * L2E2, wn2 = -2.0f * r2W1[j];
  const float w03 = r3W0[j] * L2E2, b03 = r3b0[j] * L2E2, wn3 = -2.0f * r3W1[j];

  const float C1 = r1b1[0] + sum16(r1W1[j]);
  const float C2 = r2b1[0] + sum16(r2W1[j]);
  const float C3 = r3b1[0] + sum16(r3W1[j]);
  const float caC = 0.2f - C1;
  const float cbC = -1.0f / 6.0f + (5.0f / 3.0f) * C1 - 3.0f * C2 + C3;
  const float ccC = -1.0f / 6.0f + C2 - C3;

  float ca = x0[e * 15 + 0];
  float cb = x0[e * 15 + 1];
  float cc = x0[e * 15 + 2];

  const float* up = useq + e * TT;
  float* op = out + (size_t)e * TT * 4;

  float uc0, uc1, uc2, uc3, uc4, uc5, uc6, uc7;
  {
    float4 a = *(const float4*)(up);
    float4 b = *(const float4*)(up + 4);
    uc0 = a.x; uc1 = a.y; uc2 = a.z; uc3 = a.w;
    uc4 = b.x; uc5 = b.y; uc6 = b.z; uc7 = b.w;
  }

#define STAGE(A, B, C, KA, KB, KC)                                           \
  {                                                                          \
    float rv1 = __builtin_amdgcn_rcpf(                                       \
        __builtin_amdgcn_exp2f(fmaf(w01, (A), b01)) + 1.0f);                 \
    float rv2 = __builtin_amdgcn_rcpf(                                       \
        __builtin_amdgcn_exp2f(fmaf(w02, (B), b02)) + 1.0f);                 \
    float rv3 = __builtin_amdgcn_rcpf(                                       \
        __builtin_amdgcn_exp2f(fmaf(w03, (C), b03)) + 1.0f);                 \
    float P1 = sum16(wn1 * rv1);                                             \
    float P2 = sum16(wn2 * rv2);                                             \
    float P3 = sum16(wn3 * rv3);                                             \
    KA = fmaf(-0.1f, (A), ut) - P1;                                          \
    KB = fmaf(-0.1f, (B), cbC) + fmaf(5.0f / 3.0f, P1, fmaf(-3.0f, P2, P3)); \
    KC = fmaf(-0.1f, (C), ccC) + (P2 - P3);                                  \
  }

  for (int t0 = 0; t0 < TT; t0 += K1) {
    // Prefetch next chunk's u (clamped to stay in-bounds on the last chunk).
    const int tn = (t0 + K1 <= TT - K1) ? (t0 + K1) : (TT - K1);
    const float4 na = *(const float4*)(up + tn);
    const float4 nb = *(const float4*)(up + tn + 4);

    float sc0, sc1, sc2, sc3, sc4, sc5, sc6, sc7;

#define STEP(UQ, SCQ)                                                        \
  {                                                                          \
    const float ut = fmaf(0.1f, (UQ), caC);                                  \
    SCQ = (j == 0) ? ca : ((j == 1) ? cb : cc);                              \
    float k1a, k1b, k1c, k2a, k2b, k2c, k3a, k3b, k3c, k4a, k4b, k4c;        \
    STAGE(ca, cb, cc, k1a, k1b, k1c)                                         \
    float xa = fmaf(0.5f, k1a, ca);                                          \
    float xb = fmaf(0.5f, k1b, cb);                                          \
    float xc = fmaf(0.5f, k1c, cc);                                          \
    STAGE(xa, xb, xc, k2a, k2b, k2c)                                         \
    xa = fmaf(0.5f, k2a, ca);                                                \
    xb = fmaf(0.5f, k2b, cb);                                                \
    xc = fmaf(0.5f, k2c, cc);                                                \
    STAGE(xa, xb, xc, k3a, k3b, k3c)                                         \
    xa = ca + k3a;                                                           \
    xb = cb + k3b;                                                           \
    xc = cc + k3c;                                                           \
    STAGE(xa, xb, xc, k4a, k4b, k4c)                                         \
    ca = fmaf(1.0f / 6.0f, fmaf(2.0f, k2a + k3a, k1a) + k4a, ca);            \
    cb = fmaf(1.0f / 6.0f, fmaf(2.0f, k2b + k3b, k1b) + k4b, cb);            \
    cc = fmaf(1.0f / 6.0f, fmaf(2.0f, k2c + k3c, k1c) + k4c, cc);            \
  }

    STEP(uc0, sc0)
    STEP(uc1, sc1)
    STEP(uc2, sc2)
    STEP(uc3, sc3)
    STEP(uc4, sc4)
    STEP(uc5, sc5)
    STEP(uc6, sc6)
    STEP(uc7, sc7)
#undef STEP

    // Batched output stores: lanes 0..2 write component j for 8 steps.
    if (j < 3) {
      float* p = op + t0 * 4 + j;
      p[0] = sc0;  p[4] = sc1;  p[8] = sc2;  p[12] = sc3;
      p[16] = sc4; p[20] = sc5; p[24] = sc6; p[28] = sc7;
    }

    uc0 = na.x; uc1 = na.y; uc2 = na.z; uc3 = na.w;
    uc4 = nb.x; uc5 = nb.y; uc6 = nb.z; uc7 = nb.w;
  }
#undef STAGE
}

// ---------------------------------------------------------------------------
// Phase 2: out[b,t,3] = estC(z_t). One LANE per sample (64 samples/wave),
// 32768 waves. Hidden-layer weights broadcast from LDS (ds_read_b128),
// z gathered with one base pointer + immediate offsets. No reduction.
__global__ __launch_bounds__(256) void phase2_kernel(
    const float* __restrict__ useq, const float* __restrict__ x0,
    const float* __restrict__ W0, const float* __restrict__ b0,
    const float* __restrict__ W1, const float* __restrict__ b1p,
    float* __restrict__ out) {
  // row[h] = { w0s[0..11] (= L2E2*W0 column h), b0s, w1n (= -2*W1[h]), pad }
  __shared__ float row[32][16];
  for (int idx = threadIdx.x; idx < 384; idx += 256) {
    const int i = idx >> 5, h = idx & 31;
    row[h][i] = W0[idx] * L2E2;
  }
  if (threadIdx.x < 32) {
    const int h = threadIdx.x;
    row[h][12] = b0[h] * L2E2;
    row[h][13] = -2.0f * W1[h];
  }
  __syncthreads();

  // base = b1 + sum_h W1[h]  (uniform scalar loads, constant-cached)
  float base = b1p[0];
#pragma unroll
  for (int h = 0; h < 32; ++h) base += W1[h];

  const int task = blockIdx.x * 4 + (threadIdx.x >> 6);  // wave id
  const int b = task >> 4;      // batch row (16 chunks of 64 t's per row)
  const int c = task & 15;
  const int t = c * 64 + (threadIdx.x & 63);
  const int s = (b << 10) + t;  // sample index

  float z[12];
  if (c != 0) {
    // Fast path: t >= 64, all history in-bounds. One base + imm offsets.
    const float* px = out + (size_t)s * 4;
#pragma unroll
    for (int i = 0; i < 4; ++i) {
      z[2 * i] = px[(i - 4) * 4 + 0];
      z[2 * i + 1] = px[(i - 4) * 4 + 1];
    }
    const float* pu = useq + s;
#pragma unroll
    for (int i = 0; i < 4; ++i) z[8 + i] = pu[i - 4];
  } else {
    // Edge chunk: lanes with t < 4 pull history from x0's z-part.
    const float* xrow = x0 + b * 15;
#pragma unroll
    for (int i = 0; i < 4; ++i) {
      const int s4 = t - 4 + i;
      const float* py = (s4 >= 0) ? (out + ((size_t)(b << 10) + s4) * 4)
                                  : (xrow + 3 + 2 * (i + t));
      z[2 * i] = py[0];
      z[2 * i + 1] = py[1];
      const float* pu = (s4 >= 0) ? (useq + (b << 10) + s4)
                                  : (xrow + 11 + i + t);
      z[8 + i] = pu[0];
    }
  }

  float ov = base;
#pragma unroll
  for (int h = 0; h < 32; ++h) {
    const float4 wa = *(const float4*)&row[h][0];
    const float4 wb = *(const float4*)&row[h][4];
    const float4 wc = *(const float4*)&row[h][8];
    const float2 wd = *(const float2*)&row[h][12];
    float a = wd.x;
    a = fmaf(z[0], wa.x, a); a = fmaf(z[1], wa.y, a);
    a = fmaf(z[2], wa.z, a); a = fmaf(z[3], wa.w, a);
    a = fmaf(z[4], wb.x, a); a = fmaf(z[5], wb.y, a);
    a = fmaf(z[6], wb.z, a); a = fmaf(z[7], wb.w, a);
    a = fmaf(z[8], wc.x, a); a = fmaf(z[9], wc.y, a);
    a = fmaf(z[10], wc.z, a); a = fmaf(z[11], wc.w, a);
    const float r = __builtin_amdgcn_rcpf(__builtin_amdgcn_exp2f(a) + 1.0f);
    ov = fmaf(wd.y, r, ov);
  }
  out[(size_t)s * 4 + 3] = ov;
}

// ---------------------------------------------------------------------------
extern "C" void kernel_launch(void* const* d_in, const int* in_sizes, int n_in,
                              void* d_out, int out_size, void* d_ws,
                              size_t ws_size, hipStream_t stream) {
  const float* useq = (const float*)d_in[0];
  const float* x0 = (const float*)d_in[1];
  float* out = (float*)d_out;

  phase1_kernel<<<BB / 4, 64, 0, stream>>>(
      useq, x0,
      (const float*)d_in[2], (const float*)d_in[3], (const float*)d_in[4],
      (const float*)d_in[5], (const float*)d_in[6], (const float*)d_in[7],
      (const float*)d_in[8], (const float*)d_in[9], (const float*)d_in[10],
      (const float*)d_in[11], (const float*)d_in[12], (const float*)d_in[13],
      out);

  phase2_kernel<<<(BB * 16) / 4, 256, 0, stream>>>(
      useq, x0, (const float*)d_in[14], (const float*)d_in[15],
      (const float*)d_in[16], (const float*)d_in[17], out);
}

// Round 3
// 526.942 us; speedup vs baseline: 1.5930x; 1.0339x over previous
//
#include <hip/hip_runtime.h>

#define TT 1024
#define BB 2048
#define K1 8
#define L2E2 2.8853900817779268f  // 2*log2(e)

// DPP helpers -----------------------------------------------------------------
template <int CTRL>
__device__ __forceinline__ float dpp_add(float x) {
  int y = __builtin_amdgcn_update_dpp(0, __float_as_int(x), CTRL, 0xF, 0xF, true);
  return x + __int_as_float(y);
}
// Sum within each aligned 16-lane row; result replicated in all 16 lanes.
__device__ __forceinline__ float sum16(float x) {
  x = dpp_add<0xB1>(x);   // quad_perm xor1
  x = dpp_add<0x4E>(x);   // quad_perm xor2
  x = dpp_add<0x141>(x);  // row_half_mirror
  x = dpp_add<0x140>(x);  // row_mirror
  return x;
}
// ROW_BCAST15 (0x142): row r (r>=1) gets last lane of row r-1; row0 -> 0.
__device__ __forceinline__ float bcast15(float x) {
  return __int_as_float(
      __builtin_amdgcn_update_dpp(0, __float_as_int(x), 0x142, 0xF, 0xF, true));
}

// ---------------------------------------------------------------------------
// Phase 1: sequential RK4 scan. 64 lanes per element (2048 waves, 2/SIMD).
// Rows (16 lanes): row0=NN1/state A, row1=NN2/B, row2=NN3/C, row3=NN3dup/C.
// Per stage: ONE eval stream (per-lane weights), sum16, m1/m2 = bcast15
// cascade (rows get prev rows' P), one ds_bpermute (row1 <- row2's P3).
// K = fma(-0.1,sv,cst) + uflag*0.1u + alpha*P + beta*m1 + gamma*m2 + delta*bp
//   row0: KA = -0.1A + (0.2-C1) + 0.1u - P1
//   row1: KB = -0.1B + cbC + (5/3)P1[m1] - 3P2[own] + P3[bp]
//   row2: KC = -0.1C + ccC + P2[m1] - P3[own]
//   row3: KC = -0.1C + ccC + P2[m2] - P3[own]
__global__ __launch_bounds__(256) void phase1_kernel(
    const float* __restrict__ useq, const float* __restrict__ x0,
    const float* __restrict__ r1W0, const float* __restrict__ r1b0,
    const float* __restrict__ r1W1, const float* __restrict__ r1b1,
    const float* __restrict__ r2W0, const float* __restrict__ r2b0,
    const float* __restrict__ r2W1, const float* __restrict__ r2b1,
    const float* __restrict__ r3W0, const float* __restrict__ r3b0,
    const float* __restrict__ r3W1, const float* __restrict__ r3b1,
    float* __restrict__ out) {
  const int lane = threadIdx.x & 63;
  const int row = lane >> 4;
  const int j = lane & 15;
  const int e = blockIdx.x * 4 + (threadIdx.x >> 6);

  const float* W0p = (row == 0) ? r1W0 : (row == 1) ? r2W0 : r3W0;
  const float* b0p = (row == 0) ? r1b0 : (row == 1) ? r2b0 : r3b0;
  const float* W1p = (row == 0) ? r1W1 : (row == 1) ? r2W1 : r3W1;

  const float w0s = W0p[j] * L2E2;
  const float b0s = b0p[j] * L2E2;
  const float wn = -2.0f * W1p[j];

  // C_i = b1_i + sum_j W1_i[j]  (uniform on all lanes, init-only cost)
  float C1 = r1b1[0], C2 = r2b1[0], C3 = r3b1[0];
  for (int q = 0; q < 16; ++q) {
    C1 += r1W1[q];
    C2 += r2W1[q];
    C3 += r3W1[q];
  }
  const float caC = 0.2f - C1;
  const float cbC = -1.0f / 6.0f + (5.0f / 3.0f) * C1 - 3.0f * C2 + C3;
  const float ccC = -1.0f / 6.0f + C2 - C3;

  const float cst = (row == 0) ? caC : (row == 1) ? cbC : ccC;
  const float uflag = (row == 0) ? 1.0f : 0.0f;
  const float alpha = (row == 1) ? -3.0f : -1.0f;
  const float beta = (row == 1) ? (5.0f / 3.0f) : (row == 2) ? 1.0f : 0.0f;
  const float gamma = (row == 3) ? 1.0f : 0.0f;
  const float delta = (row == 1) ? 1.0f : 0.0f;

  // bpermute: row1 lanes pull row2's P; others pull self (unused).
  const int bpaddr = 4 * (lane + ((row == 1) ? 16 : 0));

  float sv = x0[e * 15 + ((row < 2) ? row : 2)];

  const float* up = useq + e * TT;
  float* op = out + (size_t)e * TT * 4;

#define STAGE(SV, K)                                                    \
  {                                                                     \
    float rv = __builtin_amdgcn_rcpf(                                   \
        __builtin_amdgcn_exp2f(fmaf(w0s, (SV), b0s)) + 1.0f);           \
    float P = sum16(wn * rv);                                           \
    int bpi = __builtin_amdgcn_ds_bpermute(bpaddr, __float_as_int(P));  \
    float m1 = bcast15(P);                                              \
    float m2 = bcast15(m1);                                             \
    float t_ = fmaf(u01, uflag, fmaf(-0.1f, (SV), cst));                \
    float kk = fmaf(alpha, P, t_) + fmaf(beta, m1, gamma * m2);         \
    K = fmaf(delta, __int_as_float(bpi), kk);                           \
  }

#define STEP(UQ, SCQ)                                  \
  {                                                    \
    const float u01 = 0.1f * (UQ);                     \
    SCQ = sv;                                          \
    float k1, k2, k3, k4;                              \
    STAGE(sv, k1)                                      \
    float s2 = fmaf(0.5f, k1, sv);                     \
    STAGE(s2, k2)                                      \
    float s3 = fmaf(0.5f, k2, sv);                     \
    STAGE(s3, k3)                                      \
    float s4 = sv + k3;                                \
    STAGE(s4, k4)                                      \
    sv = fmaf(1.0f / 6.0f, fmaf(2.0f, k2 + k3, k1) + k4, sv); \
  }

  float uc0, uc1, uc2, uc3, uc4, uc5, uc6, uc7;
  {
    float4 a = *(const float4*)(up);
    float4 b = *(const float4*)(up + 4);
    uc0 = a.x; uc1 = a.y; uc2 = a.z; uc3 = a.w;
    uc4 = b.x; uc5 = b.y; uc6 = b.z; uc7 = b.w;
  }

  for (int t0 = 0; t0 < TT; t0 += K1) {
    const int tn = (t0 + K1 <= TT - K1) ? (t0 + K1) : (TT - K1);
    const float4 na = *(const float4*)(up + tn);
    const float4 nb = *(const float4*)(up + tn + 4);

    float sc0, sc1, sc2, sc3, sc4, sc5, sc6, sc7;
    STEP(uc0, sc0)
    STEP(uc1, sc1)
    STEP(uc2, sc2)
    STEP(uc3, sc3)
    STEP(uc4, sc4)
    STEP(uc5, sc5)
    STEP(uc6, sc6)
    STEP(uc7, sc7)

    // y[b,t,row] = state at step start; 3 lanes (j==0, row<3) store.
    if (j == 0 && row < 3) {
      float* p = op + t0 * 4 + row;
      p[0] = sc0;  p[4] = sc1;  p[8] = sc2;  p[12] = sc3;
      p[16] = sc4; p[20] = sc5; p[24] = sc6; p[28] = sc7;
    }

    uc0 = na.x; uc1 = na.y; uc2 = na.z; uc3 = na.w;
    uc4 = nb.x; uc5 = nb.y; uc6 = nb.z; uc7 = nb.w;
  }
#undef STEP
#undef STAGE
}

// ---------------------------------------------------------------------------
// Pack estC weights into d_ws, folded: wpk[h*16 + 0..11] = L2E2*W0[:,h],
// [12] = L2E2*b0[h], [13] = -2*W1[h]; wpk[512] = b1 + sum_h W1[h].
__global__ __launch_bounds__(512) void pack_kernel(
    const float* __restrict__ W0, const float* __restrict__ b0,
    const float* __restrict__ W1, const float* __restrict__ b1p,
    float* __restrict__ wpk) {
  const int i = threadIdx.x;
  if (i < 384) {
    const int r = i >> 5, h = i & 31;
    wpk[h * 16 + r] = W0[i] * L2E2;
  } else if (i < 416) {
    const int h = i - 384;
    wpk[h * 16 + 12] = b0[h] * L2E2;
    wpk[h * 16 + 13] = -2.0f * W1[h];
    wpk[h * 16 + 14] = 0.0f;
    wpk[h * 16 + 15] = 0.0f;
  } else if (i == 416) {
    float base = b1p[0];
    for (int h = 0; h < 32; ++h) base += W1[h];
    wpk[512] = base;
  }
}

// ---------------------------------------------------------------------------
// Phase 2: out[b,t,3] = estC(z_t). One lane per sample. Weights read with
// uniform addresses from wpk -> scalar loads (s_load), v_fma with SGPR src.
__global__ __launch_bounds__(256) void phase2_kernel(
    const float* __restrict__ useq, const float* __restrict__ x0,
    const float* __restrict__ wpk, float* __restrict__ out) {
  const int g = blockIdx.x * 256 + threadIdx.x;  // sample = b*1024 + t
  const int b = g >> 10;
  const int t = g & 1023;

  float z[12];
  if (t >= 4) {
    const float* px = out + (size_t)g * 4;
#pragma unroll
    for (int i = 0; i < 4; ++i) {
      z[2 * i] = px[(i - 4) * 4 + 0];
      z[2 * i + 1] = px[(i - 4) * 4 + 1];
    }
    const float* pu = useq + g;
#pragma unroll
    for (int i = 0; i < 4; ++i) z[8 + i] = pu[i - 4];
  } else {
    const float* xrow = x0 + b * 15;
#pragma unroll
    for (int i = 0; i < 4; ++i) {
      const int s4 = t - 4 + i;
      const float* py = (s4 >= 0) ? (out + ((size_t)(b << 10) + s4) * 4)
                                  : (xrow + 3 + 2 * (i + t));
      z[2 * i] = py[0];
      z[2 * i + 1] = py[1];
      const float* pu = (s4 >= 0) ? (useq + (b << 10) + s4)
                                  : (xrow + 11 + i + t);
      z[8 + i] = pu[0];
    }
  }

  float ov = wpk[512];
#pragma unroll
  for (int h = 0; h < 32; ++h) {
    const float* w = wpk + h * 16;
    float a = w[12];
    a = fmaf(z[0], w[0], a);  a = fmaf(z[1], w[1], a);
    a = fmaf(z[2], w[2], a);  a = fmaf(z[3], w[3], a);
    a = fmaf(z[4], w[4], a);  a = fmaf(z[5], w[5], a);
    a = fmaf(z[6], w[6], a);  a = fmaf(z[7], w[7], a);
    a = fmaf(z[8], w[8], a);  a = fmaf(z[9], w[9], a);
    a = fmaf(z[10], w[10], a); a = fmaf(z[11], w[11], a);
    const float r = __builtin_amdgcn_rcpf(__builtin_amdgcn_exp2f(a) + 1.0f);
    ov = fmaf(w[13], r, ov);
  }
  out[(size_t)g * 4 + 3] = ov;
}

// ---------------------------------------------------------------------------
extern "C" void kernel_launch(void* const* d_in, const int* in_sizes, int n_in,
                              void* d_out, int out_size, void* d_ws,
                              size_t ws_size, hipStream_t stream) {
  const float* useq = (const float*)d_in[0];
  const float* x0 = (const float*)d_in[1];
  float* out = (float*)d_out;
  float* wpk = (float*)d_ws;

  pack_kernel<<<1, 512, 0, stream>>>((const float*)d_in[14],
                                     (const float*)d_in[15],
                                     (const float*)d_in[16],
                                     (const float*)d_in[17], wpk);

  phase1_kernel<<<BB / 4, 256, 0, stream>>>(
      useq, x0,
      (const float*)d_in[2], (const float*)d_in[3], (const float*)d_in[4],
      (const float*)d_in[5], (const float*)d_in[6], (const float*)d_in[7],
      (const float*)d_in[8], (const float*)d_in[9], (const float*)d_in[10],
      (const float*)d_in[11], (const float*)d_in[12], (const float*)d_in[13],
      out);

  phase2_kernel<<<(BB * TT) / 256, 256, 0, stream>>>(useq, x0, wpk, out);
}